// Round 1
// baseline (47.370 us; speedup 1.0000x reference)
//
#include <hip/hip_runtime.h>

// LowFreqPenaltyLoss: mean(|truncated 2-D DCT (8x8) of each 256x256 image|)
// delta: [256,3,256,256] f32 -> scalar f32.
// Basis C[k,n] = 2*cos(pi*(2n+1)*k/512), identical for H and W (both 256).
// Per image: u[w][i] = sum_h C[i,h]*X[h,w]; low[i,j] = sum_w C[j,w]*u[w][i].

#define INV_COUNT (1.0f / 49152.0f)  // 256*3*8*8

__global__ __launch_bounds__(256, 3) void lowfreq_main(
    const float* __restrict__ delta, float* __restrict__ out)
{
    __shared__ float c_row[256][8];  // c_row[n][k] : broadcast reads by row h
    __shared__ float c_col[8][256];  // transposed : per-lane conflict-free reads
    __shared__ float pacc[4][64];

    const int t = threadIdx.x;
    const int wave = t >> 6;
    const int lane = t & 63;

    // Phase 0: DCT-II basis (unnormalized, torch_dct norm=None convention)
    {
        const float base = 3.14159265358979323846f * (2.0f * (float)t + 1.0f)
                           * (1.0f / 512.0f);
        #pragma unroll
        for (int k = 0; k < 8; ++k) {
            const float v = 2.0f * cosf(base * (float)k);
            c_row[t][k] = v;
            c_col[k][t] = v;
        }
    }
    __syncthreads();

    // Phase 1: stream 64 rows (this wave's h-range), thread owns columns
    // {lane, lane+64, lane+128, lane+192} -> coalesced dword loads.
    const float* img = delta + (size_t)blockIdx.x * 65536;
    const float* gp  = img + (wave << 6) * 256 + lane;

    float u[4][8];
    #pragma unroll
    for (int c = 0; c < 4; ++c)
        #pragma unroll
        for (int i = 0; i < 8; ++i) u[c][i] = 0.0f;

    #pragma unroll 4
    for (int r = 0; r < 64; ++r) {
        const int h = (wave << 6) + r;
        const float x0 = gp[r * 256 + 0];
        const float x1 = gp[r * 256 + 64];
        const float x2 = gp[r * 256 + 128];
        const float x3 = gp[r * 256 + 192];
        const float4 cA = *reinterpret_cast<const float4*>(&c_row[h][0]);
        const float4 cB = *reinterpret_cast<const float4*>(&c_row[h][4]);
        const float cc[8] = {cA.x, cA.y, cA.z, cA.w, cB.x, cB.y, cB.z, cB.w};
        #pragma unroll
        for (int i = 0; i < 8; ++i) {
            u[0][i] = fmaf(cc[i], x0, u[0][i]);
            u[1][i] = fmaf(cc[i], x1, u[1][i]);
            u[2][i] = fmaf(cc[i], x2, u[2][i]);
            u[3][i] = fmaf(cc[i], x3, u[3][i]);
        }
    }

    // Phase 2: per-thread partial low[i][j] over its 4 columns.
    float cw[4][8];
    #pragma unroll
    for (int c = 0; c < 4; ++c)
        #pragma unroll
        for (int j = 0; j < 8; ++j)
            cw[c][j] = c_col[j][(c << 6) + lane];  // contiguous per lane

    float v[64];
    #pragma unroll
    for (int i = 0; i < 8; ++i)
        #pragma unroll
        for (int j = 0; j < 8; ++j) {
            float s = u[0][i] * cw[0][j];
            s = fmaf(u[1][i], cw[1][j], s);
            s = fmaf(u[2][i], cw[2][j], s);
            s = fmaf(u[3][i], cw[3][j], s);
            v[(i << 3) + j] = s;
        }

    // Phase 3: slot-splitting butterfly — transpose+reduce 64 slots across the
    // wave. Invariant: after stage s, v[k] = partial sum of slot
    // (k<<s | low s bits of lane); at the end lane l holds the wave total of
    // slot l = (i<<3|j).
    #pragma unroll
    for (int s = 0; s < 6; ++s) {
        const int m = 1 << s;
        const bool bit = (lane & m) != 0;
        #pragma unroll
        for (int k = 0; k < (64 >> (s + 1)); ++k) {
            const float a = v[2 * k];      // slot bit s == 0
            const float b = v[2 * k + 1];  // slot bit s == 1
            const float keep = bit ? b : a;
            const float send = bit ? a : b;
            const float recv = __shfl_xor(send, m, 64);
            v[k] = keep + recv;            // ascending k: safe in-place
        }
    }

    pacc[wave][lane] = v[0];
    __syncthreads();

    // Phase 4: combine 4 waves, abs per (i,j), block sum, one atomic.
    if (t < 64) {
        const float s4 = pacc[0][t] + pacc[1][t] + pacc[2][t] + pacc[3][t];
        float a = fabsf(s4);
        #pragma unroll
        for (int m = 1; m < 64; m <<= 1) a += __shfl_xor(a, m, 64);
        if (t == 0) atomicAdd(out, a * INV_COUNT);
    }
}

extern "C" void kernel_launch(void* const* d_in, const int* in_sizes, int n_in,
                              void* d_out, int out_size, void* d_ws, size_t ws_size,
                              hipStream_t stream)
{
    const float* delta = (const float*)d_in[0];
    float* out = (float*)d_out;
    hipMemsetAsync(out, 0, sizeof(float) * (size_t)out_size, stream);
    lowfreq_main<<<768, 256, 0, stream>>>(delta, out);
}